// Round 2
// baseline (81.205 us; speedup 1.0000x reference)
//
#include <hip/hip_runtime.h>

// Block-sparse matrix metadata + dense reconstruction.
// Grid: X=Y=256 block rows/cols, BH=BW=32, N_BLOCKS=16384.
// Inputs:  d_in[0] = block_mask (bool -> int32, 65536)
//          d_in[1] = data (f32, 16384*32*32)
// Outputs (all FLOAT32, concatenated flat in d_out):
//   [0)           dense 8192x8192                  (67108864)
//   [67108864)    blocks: (col,row) pairs           (32768)
//   [67141632)    cols_a: (col, block_ptr) pairs    (32768)
//   [67174400)    row_start_ends_a                  (257)
//   [67174657)    rows_b: (row, block_ptr_t) pairs  (32768)
//   [67207425)    col_start_ends_b                  (257)

#define GX 256
#define GY 256
#define TILES_PER_BLOCK 8

// 512 blocks x 256 threads: blocks [0,256) -> row counts, [256,512) -> col counts
__global__ __launch_bounds__(256) void count_kernel(const int* __restrict__ mask,
                                                    int* __restrict__ row_counts,
                                                    int* __restrict__ col_counts) {
    __shared__ int s[256];
    int b = blockIdx.x, t = threadIdx.x;
    int m;
    if (b < GX) m = mask[b * GY + t] ? 1 : 0;
    else        m = mask[t * GY + (b - GX)] ? 1 : 0;
    s[t] = m;
    __syncthreads();
    for (int off = 128; off > 0; off >>= 1) {
        if (t < off) s[t] += s[t + off];
        __syncthreads();
    }
    if (t == 0) {
        if (b < GX) row_counts[b] = s[0];
        else        col_counts[b - GX] = s[0];
    }
}

// single block of 256 threads: exclusive prefix sums -> int ptrs + f32 outputs
__global__ __launch_bounds__(256) void scan_kernel(const int* __restrict__ row_counts,
                                                   const int* __restrict__ col_counts,
                                                   int* __restrict__ row_ptr,
                                                   int* __restrict__ col_ptr,
                                                   float* __restrict__ out_rse,
                                                   float* __restrict__ out_cse) {
    __shared__ int s[256];
    int t = threadIdx.x;

    // rows
    s[t] = row_counts[t];
    __syncthreads();
    for (int off = 1; off < 256; off <<= 1) {
        int own = s[t];
        int add = (t >= off) ? s[t - off] : 0;
        __syncthreads();
        s[t] = own + add;
        __syncthreads();
    }
    row_ptr[t + 1] = s[t];
    out_rse[t + 1] = (float)s[t];
    if (t == 0) { row_ptr[0] = 0; out_rse[0] = 0.0f; }
    __syncthreads();

    // cols
    s[t] = col_counts[t];
    __syncthreads();
    for (int off = 1; off < 256; off <<= 1) {
        int own = s[t];
        int add = (t >= off) ? s[t - off] : 0;
        __syncthreads();
        s[t] = own + add;
        __syncthreads();
    }
    col_ptr[t + 1] = s[t];
    out_cse[t + 1] = (float)s[t];
    if (t == 0) { col_ptr[0] = 0; out_cse[0] = 0.0f; }
}

// 256 blocks (one per block-row) x 256 threads (one per block-col)
__global__ __launch_bounds__(256) void emit_rows_kernel(const int* __restrict__ mask,
                                                        const int* __restrict__ row_ptr,
                                                        int* __restrict__ idx_grid,
                                                        float* __restrict__ out_blocks,
                                                        float* __restrict__ out_cols_a) {
    __shared__ int s[256];
    int r = blockIdx.x, c = threadIdx.x;
    int m = mask[r * GY + c] ? 1 : 0;
    s[c] = m;
    __syncthreads();
    for (int off = 1; off < 256; off <<= 1) {
        int own = s[c];
        int add = (c >= off) ? s[c - off] : 0;
        __syncthreads();
        s[c] = own + add;
        __syncthreads();
    }
    if (m) {
        int i = row_ptr[r] + s[c] - 1;  // row-major rank
        idx_grid[r * GY + c] = i;
        float fc = (float)c;
        *(float2*)&out_blocks[2 * i] = make_float2(fc, (float)r);
        *(float2*)&out_cols_a[2 * i] = make_float2(fc, (float)i);
    }
}

// 256 blocks (one per block-col) x 256 threads (one per block-row)
__global__ __launch_bounds__(256) void emit_cols_kernel(const int* __restrict__ mask,
                                                        const int* __restrict__ col_ptr,
                                                        const int* __restrict__ idx_grid,
                                                        float* __restrict__ out_rows_b) {
    __shared__ int s[256];
    int c = blockIdx.x, r = threadIdx.x;
    int m = mask[r * GY + c] ? 1 : 0;
    s[r] = m;
    __syncthreads();
    for (int off = 1; off < 256; off <<= 1) {
        int own = s[r];
        int add = (r >= off) ? s[r - off] : 0;
        __syncthreads();
        s[r] = own + add;
        __syncthreads();
    }
    if (m) {
        int j = col_ptr[c] + s[r] - 1;  // col-major rank
        int i = idx_grid[r * GY + c];
        *(float2*)&out_rows_b[2 * j] = make_float2((float)r, (float)i);
    }
}

// 8192 blocks x 256 threads, 8 tiles per block.
// dense[r*32+p][c*32+q] = data[i*1024 + q*32 + p] (blocks stored transposed); 0 if empty.
__global__ __launch_bounds__(256) void dense_kernel(const float* __restrict__ data,
                                                    const int* __restrict__ idx_grid,
                                                    const int* __restrict__ mask,
                                                    float* __restrict__ out_dense) {
    __shared__ float lds[32 * 33];
    int t = threadIdx.x;
    int w  = t & 7;   // float4 group within a 32-wide row
    int a8 = t >> 3;  // 0..31: row of tile (write phase) / source row (load phase)

    int tile0 = blockIdx.x * TILES_PER_BLOCK;
    for (int tile = tile0; tile < tile0 + TILES_PER_BLOCK; ++tile) {
        int r = tile >> 8, c = tile & 255;
        float4* dst = (float4*)out_dense + (size_t)(r * 32 + a8) * 2048 + c * 8 + w;

        if (!mask[tile]) {
            *dst = make_float4(0.f, 0.f, 0.f, 0.f);
            continue;
        }

        int i = idx_grid[tile];
        // load 32x32 f32 block: thread t loads elements 4t..4t+3
        // k = q*32 + p  ->  q = t>>3, p = (t&7)*4 + j ; lds[q*33+p] = value
        const float4* src4 = (const float4*)(data + (size_t)i * 1024);
        float4 v = src4[t];
        int q = a8, p0 = w * 4;
        lds[q * 33 + p0 + 0] = v.x;
        lds[q * 33 + p0 + 1] = v.y;
        lds[q * 33 + p0 + 2] = v.z;
        lds[q * 33 + p0 + 3] = v.w;
        __syncthreads();
        // write row p=a8, cols 4w..4w+3:  out[p][q'] = lds[q'*33+p]
        float4 f;
        f.x = lds[(4 * w + 0) * 33 + a8];
        f.y = lds[(4 * w + 1) * 33 + a8];
        f.z = lds[(4 * w + 2) * 33 + a8];
        f.w = lds[(4 * w + 3) * 33 + a8];
        *dst = f;
        __syncthreads();  // LDS reused next tile
    }
}

extern "C" void kernel_launch(void* const* d_in, const int* in_sizes, int n_in,
                              void* d_out, int out_size, void* d_ws, size_t ws_size,
                              hipStream_t stream) {
    const int* mask = (const int*)d_in[0];      // bool -> int32, 65536
    const float* data = (const float*)d_in[1];  // f32, 16777216

    // workspace layout (ints)
    int* ws = (int*)d_ws;
    int* row_counts = ws;            // 256
    int* col_counts = ws + 256;      // 256
    int* row_ptr    = ws + 512;      // 257
    int* col_ptr    = ws + 769;      // 257
    int* idx_grid   = ws + 1032;     // 65536

    // output layout (f32 elements)
    float* out = (float*)d_out;
    float* out_blocks = out + 67108864ull;     // 32768
    float* out_cols_a = out_blocks + 32768;    // 32768
    float* out_rse    = out_cols_a + 32768;    // 257
    float* out_rows_b = out_rse + 257;         // 32768
    float* out_cse    = out_rows_b + 32768;    // 257

    count_kernel<<<512, 256, 0, stream>>>(mask, row_counts, col_counts);
    scan_kernel<<<1, 256, 0, stream>>>(row_counts, col_counts, row_ptr, col_ptr,
                                       out_rse, out_cse);
    emit_rows_kernel<<<256, 256, 0, stream>>>(mask, row_ptr, idx_grid,
                                              out_blocks, out_cols_a);
    emit_cols_kernel<<<256, 256, 0, stream>>>(mask, col_ptr, idx_grid, out_rows_b);
    dense_kernel<<<8192, 256, 0, stream>>>(data, idx_grid, mask, out);
}

// Round 3
// 75.596 us; speedup vs baseline: 1.0742x; 1.0742x over previous
//
#include <hip/hip_runtime.h>

// Block-sparse matrix metadata + dense reconstruction.
// Grid: X=Y=256 block rows/cols, BH=BW=32, N_BLOCKS=16384.
// Inputs:  d_in[0] = block_mask (bool -> int32, 65536)
//          d_in[1] = data (f32, 16384*32*32)
// Outputs (all FLOAT32, concatenated flat in d_out):
//   [0)           dense 8192x8192                  (67108864)
//   [67108864)    blocks: (col,row) pairs           (32768)
//   [67141632)    cols_a: (col, block_ptr) pairs    (32768)
//   [67174400)    row_start_ends_a                  (257)
//   [67174657)    rows_b: (row, block_ptr_t) pairs  (32768)
//   [67207425)    col_start_ends_b                  (257)

#define GX 256
#define GY 256
#define STRIP 8  // tiles per dense block (one block-row strip of 8 adjacent cols)

// 512 blocks x 256 threads: blocks [0,256) -> row counts, [256,512) -> col counts
__global__ __launch_bounds__(256) void count_kernel(const int* __restrict__ mask,
                                                    int* __restrict__ row_counts,
                                                    int* __restrict__ col_counts) {
    __shared__ int s[256];
    int b = blockIdx.x, t = threadIdx.x;
    int m;
    if (b < GX) m = mask[b * GY + t] ? 1 : 0;
    else        m = mask[t * GY + (b - GX)] ? 1 : 0;
    s[t] = m;
    __syncthreads();
    for (int off = 128; off > 0; off >>= 1) {
        if (t < off) s[t] += s[t + off];
        __syncthreads();
    }
    if (t == 0) {
        if (b < GX) row_counts[b] = s[0];
        else        col_counts[b - GX] = s[0];
    }
}

// 256 blocks (one per block-row) x 256 threads.
// Each block: scan row_counts -> its own row_start (block 0 also writes out_rse),
// then scan its mask row -> emit blocks / cols_a / idx_grid.
__global__ __launch_bounds__(256) void emit_rows_kernel(const int* __restrict__ mask,
                                                        const int* __restrict__ row_counts,
                                                        int* __restrict__ idx_grid,
                                                        float* __restrict__ out_blocks,
                                                        float* __restrict__ out_cols_a,
                                                        float* __restrict__ out_rse) {
    __shared__ int s[256];
    int r = blockIdx.x, c = threadIdx.x;

    // inclusive scan of row_counts
    s[c] = row_counts[c];
    __syncthreads();
    for (int off = 1; off < 256; off <<= 1) {
        int own = s[c];
        int add = (c >= off) ? s[c - off] : 0;
        __syncthreads();
        s[c] = own + add;
        __syncthreads();
    }
    if (r == 0) {
        out_rse[c + 1] = (float)s[c];
        if (c == 0) out_rse[0] = 0.0f;
    }
    int row_start = (r == 0) ? 0 : s[r - 1];
    __syncthreads();

    // scan this row of the mask
    int m = mask[r * GY + c] ? 1 : 0;
    s[c] = m;
    __syncthreads();
    for (int off = 1; off < 256; off <<= 1) {
        int own = s[c];
        int add = (c >= off) ? s[c - off] : 0;
        __syncthreads();
        s[c] = own + add;
        __syncthreads();
    }
    if (m) {
        int i = row_start + s[c] - 1;  // row-major rank
        idx_grid[r * GY + c] = i;
        float fc = (float)c;
        *(float2*)&out_blocks[2 * i] = make_float2(fc, (float)r);
        *(float2*)&out_cols_a[2 * i] = make_float2(fc, (float)i);
    }
}

// 256 blocks (one per block-col) x 256 threads.
__global__ __launch_bounds__(256) void emit_cols_kernel(const int* __restrict__ mask,
                                                        const int* __restrict__ col_counts,
                                                        const int* __restrict__ idx_grid,
                                                        float* __restrict__ out_rows_b,
                                                        float* __restrict__ out_cse) {
    __shared__ int s[256];
    int c = blockIdx.x, r = threadIdx.x;

    // inclusive scan of col_counts
    s[r] = col_counts[r];
    __syncthreads();
    for (int off = 1; off < 256; off <<= 1) {
        int own = s[r];
        int add = (r >= off) ? s[r - off] : 0;
        __syncthreads();
        s[r] = own + add;
        __syncthreads();
    }
    if (c == 0) {
        out_cse[r + 1] = (float)s[r];
        if (r == 0) out_cse[0] = 0.0f;
    }
    int col_start = (c == 0) ? 0 : s[c - 1];
    __syncthreads();

    // scan this column of the mask
    int m = mask[r * GY + c] ? 1 : 0;
    s[r] = m;
    __syncthreads();
    for (int off = 1; off < 256; off <<= 1) {
        int own = s[r];
        int add = (r >= off) ? s[r - off] : 0;
        __syncthreads();
        s[r] = own + add;
        __syncthreads();
    }
    if (m) {
        int j = col_start + s[r] - 1;  // col-major rank
        int i = idx_grid[r * GY + c];
        *(float2*)&out_rows_b[2 * j] = make_float2((float)r, (float)i);
    }
}

// 8192 blocks x 256 threads; each block = one strip of 8 adjacent tiles in a block-row.
// Stage transposed strip in LDS (pitch 260 keeps b128 reads 16B-aligned),
// one sync, then 32 rows x 1KB fully-contiguous per-wave stores.
// dense[r*32+p][c*32+q] = data[i*1024 + q*32 + p] (blocks stored transposed); 0 if empty.
__global__ __launch_bounds__(256) void dense_kernel(const float* __restrict__ data,
                                                    const int* __restrict__ idx_grid,
                                                    const int* __restrict__ mask,
                                                    float* __restrict__ out_dense) {
    __shared__ float L[32 * 260];  // [p][qq], pitch 260 floats (1040B, 16B-aligned rows)
    int t = threadIdx.x;
    int q  = t >> 3;         // 0..31: source row within tile
    int p0 = (t & 7) * 4;    // 4 consecutive output rows

    int tile0 = blockIdx.x * STRIP;
    int r  = tile0 >> 8;
    int c0 = tile0 & 255;

    #pragma unroll
    for (int k = 0; k < STRIP; ++k) {
        int tile = tile0 + k;
        int qq = k * 32 + q;
        float4 v = make_float4(0.f, 0.f, 0.f, 0.f);
        if (mask[tile]) {
            const float4* src4 = (const float4*)(data + (size_t)idx_grid[tile] * 1024);
            v = src4[t];
        }
        L[(p0 + 0) * 260 + qq] = v.x;
        L[(p0 + 1) * 260 + qq] = v.y;
        L[(p0 + 2) * 260 + qq] = v.z;
        L[(p0 + 3) * 260 + qq] = v.w;
    }
    __syncthreads();

    // write phase: wave w at iter handles output row p = iter*4 + w (256 floats = 1KB)
    float4* outv = (float4*)out_dense;
    int u = t & 63, w = t >> 6;
    #pragma unroll
    for (int iter = 0; iter < 8; ++iter) {
        int p = iter * 4 + w;
        const float4* lrow = (const float4*)&L[p * 260];
        float4 f = lrow[u];
        outv[(size_t)(r * 32 + p) * 2048 + c0 * 8 + u] = f;
    }
}

extern "C" void kernel_launch(void* const* d_in, const int* in_sizes, int n_in,
                              void* d_out, int out_size, void* d_ws, size_t ws_size,
                              hipStream_t stream) {
    const int* mask = (const int*)d_in[0];      // bool -> int32, 65536
    const float* data = (const float*)d_in[1];  // f32, 16777216

    // workspace layout (ints)
    int* ws = (int*)d_ws;
    int* row_counts = ws;            // 256
    int* col_counts = ws + 256;      // 256
    int* idx_grid   = ws + 512;      // 65536

    // output layout (f32 elements)
    float* out = (float*)d_out;
    float* out_blocks = out + 67108864ull;     // 32768
    float* out_cols_a = out_blocks + 32768;    // 32768
    float* out_rse    = out_cols_a + 32768;    // 257
    float* out_rows_b = out_rse + 257;         // 32768
    float* out_cse    = out_rows_b + 32768;    // 257

    count_kernel<<<512, 256, 0, stream>>>(mask, row_counts, col_counts);
    emit_rows_kernel<<<256, 256, 0, stream>>>(mask, row_counts, idx_grid,
                                              out_blocks, out_cols_a, out_rse);
    emit_cols_kernel<<<256, 256, 0, stream>>>(mask, col_counts, idx_grid,
                                              out_rows_b, out_cse);
    dense_kernel<<<8192, 256, 0, stream>>>(data, idx_grid, mask, out);
}

// Round 4
// 53.085 us; speedup vs baseline: 1.5297x; 1.4241x over previous
//
#include <hip/hip_runtime.h>

// Block-sparse matrix metadata + dense reconstruction — fused 2-kernel version.
// Grid: X=Y=256 block rows/cols, BH=BW=32, N_BLOCKS=16384.
// Inputs:  d_in[0] = block_mask (bool -> int32, 65536)
//          d_in[1] = data (f32, 16384*32*32)
// Outputs (all FLOAT32, concatenated flat in d_out):
//   [0)           dense 8192x8192                  (67108864)
//   [67108864)    blocks: (col,row) pairs           (32768)
//   [67141632)    cols_a: (col, block_ptr) pairs    (32768)
//   [67174400)    row_start_ends_a                  (257)
//   [67174657)    rows_b: (row, block_ptr_t) pairs  (32768)
//   [67207425)    col_start_ends_b                  (257)

#define GX 256
#define GY 256
#define STRIP 8
#define DENSE_BLOCKS 8192  // 65536 tiles / 8 per block

typedef float f32x4 __attribute__((ext_vector_type(4)));

// K1: 512 blocks x 256 threads.
// blocks [0,256): row b -> row_counts[b] + packed bit row (8 words) via ballot
// blocks [256,512): col (b-256) -> col_counts
__global__ __launch_bounds__(256) void count_kernel(const int* __restrict__ mask,
                                                    int* __restrict__ row_counts,
                                                    int* __restrict__ col_counts,
                                                    unsigned* __restrict__ bits) {
    __shared__ int s[4];
    int b = blockIdx.x, t = threadIdx.x, lane = t & 63, wv = t >> 6;
    int m;
    if (b < GX) m = mask[b * GY + t] ? 1 : 0;
    else        m = mask[t * GY + (b - GX)] ? 1 : 0;
    unsigned long long bl = __ballot(m);
    if (b < GX && lane == 0) {
        bits[b * 8 + wv * 2]     = (unsigned)bl;
        bits[b * 8 + wv * 2 + 1] = (unsigned)(bl >> 32);
    }
    if (lane == 0) s[wv] = __popcll(bl);
    __syncthreads();
    if (t == 0) {
        int tot = s[0] + s[1] + s[2] + s[3];
        if (b < GX) row_counts[b] = tot;
        else        col_counts[b - GX] = tot;
    }
}

// inclusive scan of one value per thread across 256 threads (2 barriers)
__device__ __forceinline__ int block_scan256_incl(int v, int* wsum) {
    int t = threadIdx.x, lane = t & 63, wv = t >> 6;
    __syncthreads();  // protect wsum reuse across calls
    #pragma unroll
    for (int d = 1; d < 64; d <<= 1) {
        int o = __shfl_up(v, d, 64);
        if (lane >= d) v += o;
    }
    if (lane == 63) wsum[wv] = v;
    __syncthreads();
    int s0 = wsum[0], s1 = wsum[1], s2 = wsum[2];
    int add = 0;
    if (wv >= 1) add += s0;
    if (wv >= 2) add += s1;
    if (wv >= 3) add += s2;
    return v + add;
}

// count of set bits at positions < c in an 8-word (256-bit) row; c uniform.
__device__ __forceinline__ int prefix_bits(const unsigned* w8, int c) {
    int full = c >> 5, rem = c & 31;
    int s = 0;
    #pragma unroll
    for (int k = 0; k < 8; ++k)
        if (k < full) s += __popc(w8[k]);
    if (rem) s += __popc(w8[full] & ((1u << rem) - 1u));
    return s;
}

// K2: 8704 blocks x 256 threads.
//  bid < 8192          : dense strip (8 adjacent tiles of one block-row)
//  8192 <= bid < 8448  : emit row (blocks / cols_a / row_start_ends)
//  8448 <= bid         : emit col (rows_b / col_start_ends)
__global__ __launch_bounds__(256) void mega_kernel(const float* __restrict__ data,
                                                   const int* __restrict__ mask,
                                                   const int* __restrict__ row_counts,
                                                   const int* __restrict__ col_counts,
                                                   const unsigned* __restrict__ bits,
                                                   float* __restrict__ out) {
    __shared__ float L[32 * 260];
    __shared__ int sc[256];
    __shared__ int wsum[4];

    int bid = blockIdx.x, t = threadIdx.x;

    float* out_blocks = out + 67108864ull;
    float* out_cols_a = out_blocks + 32768;
    float* out_rse    = out_cols_a + 32768;
    float* out_rows_b = out_rse + 257;
    float* out_cse    = out_rows_b + 32768;

    if (bid < DENSE_BLOCKS) {
        // ---------- dense strip ----------
        int tile0 = bid * STRIP;
        int r = tile0 >> 8, c0 = tile0 & 255;

        int incl = block_scan256_incl(row_counts[t], wsum);
        sc[t] = incl;
        __syncthreads();
        int row_start = (r == 0) ? 0 : sc[r - 1];

        unsigned w8[8];
        #pragma unroll
        for (int k = 0; k < 8; ++k) w8[k] = bits[r * 8 + k];  // wave-uniform -> SALU

        int q = t >> 3, p0 = (t & 7) * 4;
        #pragma unroll
        for (int k = 0; k < STRIP; ++k) {
            int c = c0 + k;
            int qq = k * 32 + q;
            f32x4 v = (f32x4)0.0f;
            if ((w8[c >> 5] >> (c & 31)) & 1u) {
                int i = row_start + prefix_bits(w8, c);
                const f32x4* src4 = (const f32x4*)(data + (size_t)i * 1024);
                v = src4[t];
            }
            L[(p0 + 0) * 260 + qq] = v[0];
            L[(p0 + 1) * 260 + qq] = v[1];
            L[(p0 + 2) * 260 + qq] = v[2];
            L[(p0 + 3) * 260 + qq] = v[3];
        }
        __syncthreads();

        int u = t & 63, wv = t >> 6;
        f32x4* outv = (f32x4*)out;
        #pragma unroll
        for (int iter = 0; iter < 8; ++iter) {
            int p = iter * 4 + wv;
            const f32x4* lrow = (const f32x4*)&L[p * 260];
            f32x4 f = lrow[u];
            __builtin_nontemporal_store(f, &outv[(size_t)(r * 32 + p) * 2048 + c0 * 8 + u]);
        }
    } else if (bid < DENSE_BLOCKS + 256) {
        // ---------- emit rows ----------
        int r = bid - DENSE_BLOCKS;

        int rc = row_counts[t];
        int incl = block_scan256_incl(rc, wsum);
        sc[t] = incl;
        __syncthreads();
        if (r == 0) {
            out_rse[t + 1] = (float)incl;
            if (t == 0) out_rse[0] = 0.0f;
        }
        int row_start = (r == 0) ? 0 : sc[r - 1];

        int m = mask[r * GY + t] ? 1 : 0;
        int mi = block_scan256_incl(m, wsum);
        if (m) {
            int i = row_start + mi - 1;  // row-major rank
            float fc = (float)t;
            *(float2*)&out_blocks[2 * i] = make_float2(fc, (float)r);
            *(float2*)&out_cols_a[2 * i] = make_float2(fc, (float)i);
        }
    } else {
        // ---------- emit cols ----------
        int c = bid - (DENSE_BLOCKS + 256);

        int rc = row_counts[t];
        int incl_r = block_scan256_incl(rc, wsum);
        int row_start_own = incl_r - rc;  // exclusive prefix: rank offset of row t

        int incl_c = block_scan256_incl(col_counts[t], wsum);
        sc[t] = incl_c;
        __syncthreads();
        if (c == 0) {
            out_cse[t + 1] = (float)incl_c;
            if (t == 0) out_cse[0] = 0.0f;
        }
        int col_start = (c == 0) ? 0 : sc[c - 1];

        // row t's packed bits; c is uniform
        const unsigned* wp = bits + t * 8;
        int pc = 0;
        for (int k = 0; k < (c >> 5); ++k) pc += __popc(wp[k]);  // uniform trip count
        unsigned wc = wp[c >> 5];
        if (c & 31) pc += __popc(wc & ((1u << (c & 31)) - 1u));
        int m = (wc >> (c & 31)) & 1;
        int i = row_start_own + pc;  // row-major rank of (t, c)

        int ji = block_scan256_incl(m, wsum);
        if (m) {
            int j = col_start + ji - 1;  // col-major rank
            *(float2*)&out_rows_b[2 * j] = make_float2((float)t, (float)i);
        }
    }
}

extern "C" void kernel_launch(void* const* d_in, const int* in_sizes, int n_in,
                              void* d_out, int out_size, void* d_ws, size_t ws_size,
                              hipStream_t stream) {
    const int* mask = (const int*)d_in[0];      // bool -> int32, 65536
    const float* data = (const float*)d_in[1];  // f32, 16777216

    int* ws = (int*)d_ws;
    int* row_counts = ws;                       // 256
    int* col_counts = ws + 256;                 // 256
    unsigned* bits  = (unsigned*)(ws + 512);    // 2048 words (256 rows x 8)

    float* out = (float*)d_out;

    count_kernel<<<512, 256, 0, stream>>>(mask, row_counts, col_counts, bits);
    mega_kernel<<<DENSE_BLOCKS + 512, 256, 0, stream>>>(data, mask, row_counts,
                                                        col_counts, bits, out);
}